// Round 13
// baseline (320.057 us; speedup 1.0000x reference)
//
#include <hip/hip_runtime.h>

#define SLEN 2048
#define NHEADS 16
#define HDIM 128

typedef __attribute__((ext_vector_type(8))) short bf16x8;
typedef __attribute__((ext_vector_type(4))) float f32x4;
typedef __attribute__((ext_vector_type(16))) float f32x16;

__device__ __forceinline__ unsigned short f2bf(float f) {
  union { float f; unsigned u; } v; v.f = f;
  unsigned r = v.u + 0x7FFFu + ((v.u >> 16) & 1u);
  return (unsigned short)(r >> 16);
}

__device__ __forceinline__ float bf2f(unsigned short h) {
  union { unsigned u; float f; } v; v.u = (unsigned)h << 16;
  return v.f;
}

__device__ __forceinline__ unsigned pkbf(float a, float b) {
  unsigned r;
  asm("v_cvt_pk_bf16_f32 %0, %1, %2" : "=v"(r) : "v"(a), "v"(b));
  return r;
}

__device__ __forceinline__ void gload16(const void* g, void* l) {
  __builtin_amdgcn_global_load_lds(
      (const __attribute__((address_space(1))) unsigned int*)g,
      (__attribute__((address_space(3))) unsigned int*)l, 16, 0, 0);
}

// ------------- fused f32 -> bf16 conversion for q, Wq, lat, Wkv -------------
__global__ __launch_bounds__(256) void cvt_all(const float* __restrict__ q,
                                               const float* __restrict__ Wq,
                                               const float* __restrict__ lat,
                                               const float* __restrict__ Wkv,
                                               unsigned short* __restrict__ qo,
                                               unsigned short* __restrict__ Wqo,
                                               unsigned short* __restrict__ lato,
                                               unsigned short* __restrict__ Wkvo) {
  const int blk = blockIdx.x;
  const float* in;
  unsigned short* out;
  int base;
  if (blk < 4096)      { in = q;    out = qo;    base = 0; }
  else if (blk < 6144) { in = Wq;   out = Wqo;   base = 4096; }
  else if (blk < 7168) { in = lat;  out = lato;  base = 6144; }
  else                 { in = Wkv;  out = Wkvo;  base = 7168; }
  const int i = (blk - base) * 256 + threadIdx.x;
  const float4* p = reinterpret_cast<const float4*>(in) + (size_t)i * 2;
  float4 a = p[0], b = p[1];
  uint4 o;
  o.x = (unsigned)f2bf(a.x) | ((unsigned)f2bf(a.y) << 16);
  o.y = (unsigned)f2bf(a.z) | ((unsigned)f2bf(a.w) << 16);
  o.z = (unsigned)f2bf(b.x) | ((unsigned)f2bf(b.y) << 16);
  o.w = (unsigned)f2bf(b.z) | ((unsigned)f2bf(b.w) << 16);
  reinterpret_cast<uint4*>(out)[i] = o;
}

// ------------- Wout conversion, deferred to after attention -------------
__global__ __launch_bounds__(256) void cvt_w(const float* __restrict__ in,
                                             unsigned short* __restrict__ out) {
  const int i = blockIdx.x * 256 + threadIdx.x;
  const float4* p = reinterpret_cast<const float4*>(in) + (size_t)i * 2;
  float4 a = p[0], b = p[1];
  uint4 o;
  o.x = (unsigned)f2bf(a.x) | ((unsigned)f2bf(a.y) << 16);
  o.y = (unsigned)f2bf(a.z) | ((unsigned)f2bf(a.w) << 16);
  o.z = (unsigned)f2bf(b.x) | ((unsigned)f2bf(b.y) << 16);
  o.w = (unsigned)f2bf(b.z) | ((unsigned)f2bf(b.w) << 16);
  reinterpret_cast<uint4*>(out)[i] = o;
}

// ---------------- C = A[M,K] * B[N,K]^T, bf16 in, f32 acc ----------------
// R8-verified: 128x128 tile, BK=32, 4-slot LDS ring (64 KiB), counted
// vmcnt(8) — never drains mid-loop; ONE raw barrier per iter. Both-sides
// XOR chunk swizzle. XCD swizzle (grid%8==0). blockIdx.z batches.
template <bool OUT_F32>
__global__ __launch_bounds__(256, 2) void gemm_bt(const unsigned short* __restrict__ A,
                                                  const unsigned short* __restrict__ B,
                                                  void* __restrict__ Cv,
                                                  int M, int N, int K,
                                                  size_t zB, size_t zC, float scale) {
  __shared__ unsigned short As[4][128 * 32];
  __shared__ unsigned short Bs[4][128 * 32];
  const int tid = threadIdx.x;
  const int lane = tid & 63, wid = tid >> 6;
  const int g = lane >> 4, q = lane & 15;
  const int nbx = N >> 7;
  const int cpx = gridDim.x >> 3;
  const int bid = (blockIdx.x & 7) * cpx + (blockIdx.x >> 3);
  const int bx = bid % nbx, by = bid / nbx;
  const int tM = by << 7, tN = bx << 7;
  const int wm = (wid >> 1) * 64, wn = (wid & 1) * 64;
  const size_t zoff = (size_t)blockIdx.z;
  B += zoff * zB;

  const int sr = tid >> 2, sc = tid & 3;
  const int scs = sc ^ (sr & 3);
  const unsigned short* gA0 = A + (size_t)(tM + sr) * K + (scs << 3);
  const unsigned short* gA1 = A + (size_t)(tM + 64 + sr) * K + (scs << 3);
  const unsigned short* gB0 = B + (size_t)(tN + sr) * K + (scs << 3);
  const unsigned short* gB1 = B + (size_t)(tN + 64 + sr) * K + (scs << 3);

  const int nk = K >> 5;
  const int gq = g ^ (q & 3);

  auto STAGE = [&](int slot, int kt) {
    const size_t ko = (size_t)kt << 5;
    unsigned short* ad = &As[slot][0] + tid * 8;
    unsigned short* bd = &Bs[slot][0] + tid * 8;
    gload16(gA0 + ko, ad);
    gload16(gA1 + ko, ad + 2048);
    gload16(gB0 + ko, bd);
    gload16(gB1 + ko, bd + 2048);
  };

  STAGE(0, 0); STAGE(1, 1); STAGE(2, 2);

  f32x4 acc[4][4] = {};

  for (int t = 0; t < nk; ++t) {
    if (t + 2 < nk)      asm volatile("s_waitcnt vmcnt(8)" ::: "memory");
    else if (t + 1 < nk) asm volatile("s_waitcnt vmcnt(4)" ::: "memory");
    else                 asm volatile("s_waitcnt vmcnt(0)" ::: "memory");
    __builtin_amdgcn_s_barrier();
    if (t + 3 < nk) STAGE((t + 3) & 3, t + 3);

    const int s = t & 3;
    bf16x8 af[4], bfr[4];
#pragma unroll
    for (int i = 0; i < 4; ++i)
      af[i] = *(const bf16x8*)&As[s][(wm + i * 16 + q) * 32 + gq * 8];
#pragma unroll
    for (int j = 0; j < 4; ++j)
      bfr[j] = *(const bf16x8*)&Bs[s][(wn + j * 16 + q) * 32 + gq * 8];
    __builtin_amdgcn_s_setprio(1);
#pragma unroll
    for (int i = 0; i < 4; ++i)
#pragma unroll
      for (int j = 0; j < 4; ++j)
        acc[i][j] = __builtin_amdgcn_mfma_f32_16x16x32_bf16(af[i], bfr[j], acc[i][j], 0, 0, 0);
    __builtin_amdgcn_s_setprio(0);
  }

  if constexpr (OUT_F32) {
    float* C = (float*)Cv + zoff * zC;
#pragma unroll
    for (int i = 0; i < 4; ++i)
#pragma unroll
      for (int j = 0; j < 4; ++j)
#pragma unroll
        for (int r = 0; r < 4; ++r)
          C[(size_t)(tM + wm + i * 16 + g * 4 + r) * N + (tN + wn + j * 16 + q)] =
              acc[i][j][r] * scale;
  } else {
    unsigned short* C = (unsigned short*)Cv + zoff * zC;
#pragma unroll
    for (int i = 0; i < 4; ++i)
#pragma unroll
      for (int j = 0; j < 4; ++j)
#pragma unroll
        for (int r = 0; r < 4; ++r)
          C[(size_t)(tM + wm + i * 16 + g * 4 + r) * N + (tN + wn + j * 16 + q)] =
              f2bf(acc[i][j][r] * scale);
  }
}

// ------------- causal flash attention, 8-wave blocks, 4-way KV-split -------------
// Grid 512 x 512 threads: s4 = bid&3, pr = (bid>>2)&3, bh = bid>>4.
// Block handles q-tiles {7-pr, pr} (256 rows, wave w owns rows w*32..),
// KV quarter s4 of each -> UNIFORM 9 iters/block. LDS 64 KiB (K dbuf 32K +
// V dbuf 32K) -> 2 blocks/CU = 16 waves/CU. Per-thread staging halves
// (2 K-loads + 2 V-loads per tile): top vmcnt(2)=K_t, post-softmax
// vmcnt(4)=V_t; next tile's 4 loads stay in flight across both waits.
// Same R8 inner math; XOR-swizzled K (^row&15) / VT (^row&7).
__global__ __launch_bounds__(512, 4) void mla_attn(const unsigned short* __restrict__ Q,
                                                   const unsigned short* __restrict__ K,
                                                   const unsigned short* __restrict__ VT,
                                                   unsigned short* __restrict__ Op0,
                                                   unsigned short* __restrict__ Op1,
                                                   float* __restrict__ Stats) {
  __shared__ unsigned short Ks[2][64 * 128];   // [kv][d], swizzled, 32 KiB
  __shared__ unsigned short Vs[2][128 * 64];   // [d][kv], swizzled, 32 KiB

  const int tid = threadIdx.x, lane = tid & 63, w = tid >> 6;  // w in [0,8)
  const int q5 = lane & 31, half = lane >> 5, q7 = lane & 7;
  const int s4 = blockIdx.x & 3;
  const int pr = (blockIdx.x >> 2) & 3;
  const int bh = blockIdx.x >> 4;
  const int head = bh & 15, b = bh >> 4;

  const unsigned short* Kbase = K + (size_t)(b * 2048) * 2048 + head * 128;
  const unsigned short* Vbase = VT + (size_t)(b * 2048 + head * 128) * 2048;

  // staging source coords (pre-swizzled); 512 thr cover a 64x128 tile in 2 loads
  const int r0 = tid >> 4, c0 = tid & 15;               // K: rows r0, r0+32
  const unsigned short* kS = Kbase + (size_t)r0 * 2048 + ((c0 ^ (r0 & 15)) << 3);
  const int d0 = tid >> 3, c3 = tid & 7;                // VT: rows d0, d0+64
  const unsigned short* vS = Vbase + (size_t)d0 * 2048 + ((c3 ^ (d0 & 7)) << 3);

  const int arow0 = q5 * 256;   // K LDS row byte base (+ m*8192)
  const int vrow0 = q5 * 128;   // VT LDS row byte base (+ nf*4096)
  const int q15 = q5 & 15;      // K read-side swizzle term (row&15)

  for (int t2 = 0; t2 < 2; ++t2) {
    const int qt = t2 ? pr : 7 - pr;
    const int kt0 = (qt + 1) * s4;        // KVBLK=64 tiles; T = 4(qt+1) split 4 ways
    const int ktN = (qt + 1) * (s4 + 1);
    const int myq = qt * 256 + w * 32 + q5;
    const unsigned short* Qrow = Q + (size_t)(b * 2048 + myq) * 2048 + head * 128;

    bf16x8 qf[8];
#pragma unroll
    for (int ks = 0; ks < 8; ++ks)
      qf[ks] = *(const bf16x8*)((const char*)Qrow + ks * 32 + half * 16);

    __syncthreads();  // protect LDS against previous q-tile's readers

    // prologue: stage tile kt0 (K loads first, then V -- FIFO order matters)
    {
      unsigned short* kd = &Ks[kt0 & 1][0] + tid * 8;
      unsigned short* vd = &Vs[kt0 & 1][0] + tid * 8;
      const unsigned short* ks2 = kS + (size_t)(kt0 * 64) * 2048;
      const unsigned short* vs2 = vS + kt0 * 64;
      gload16(ks2, kd);
      gload16(ks2 + (size_t)32 * 2048, kd + 4096);
      gload16(vs2, vd);
      gload16(vs2 + (size_t)64 * 2048, vd + 4096);
    }

    float m2 = -1e30f, l = 0.f;
    f32x16 o[4];
#pragma unroll
    for (int i = 0; i < 16; ++i) { o[0][i] = 0.f; o[1][i] = 0.f; o[2][i] = 0.f; o[3][i] = 0.f; }

    for (int kt = kt0; kt < ktN; ++kt) {
      const int cur = kt & 1;
      // wait K_t only (V_t + next tile's loads stay in flight)
      asm volatile("s_waitcnt vmcnt(2)" ::: "memory");
      __builtin_amdgcn_s_barrier();

      if (kt + 1 < ktN) {  // stage tile kt+1: K first, then V
        unsigned short* kd = &Ks[cur ^ 1][0] + tid * 8;
        unsigned short* vd = &Vs[cur ^ 1][0] + tid * 8;
        const unsigned short* ks2 = kS + (size_t)((kt + 1) * 64) * 2048;
        const unsigned short* vs2 = vS + (kt + 1) * 64;
        gload16(ks2, kd);
        gload16(ks2 + (size_t)32 * 2048, kd + 4096);
        gload16(vs2, vd);
        gload16(vs2 + (size_t)64 * 2048, vd + 4096);
      }

      // ---- QK^T: St[kv][q], A = K rows (LDS), B = Q (regs, pre-scaled) ----
      f32x16 st[2];
#pragma unroll
      for (int i = 0; i < 16; ++i) { st[0][i] = 0.f; st[1][i] = 0.f; }
      const char* kb = (const char*)&Ks[cur][0];
      __builtin_amdgcn_s_setprio(1);
#pragma unroll
      for (int ks = 0; ks < 8; ++ks) {
        const int cd = ks * 2 + half;
#pragma unroll
        for (int m = 0; m < 2; ++m) {
          bf16x8 kf = *(const bf16x8*)(kb + arow0 + m * 8192 + ((cd ^ q15) << 4));
          st[m] = __builtin_amdgcn_mfma_f32_32x32x16_bf16(kf, qf[ks], st[m], 0, 0, 0);
        }
      }
      __builtin_amdgcn_s_setprio(0);

      // ---- softmax in exp2 space (lane owns q-col q5; 32 kv values) ----
      float t[32];
      const int kvb = kt * 64;
      const bool needmask = (kvb + 63 > qt * 256 + w * 32);
#pragma unroll
      for (int m = 0; m < 2; ++m)
#pragma unroll
        for (int r = 0; r < 16; ++r) {
          float sv = st[m][r];
          if (needmask) {
            const int kvloc = m * 32 + (r & 3) + 8 * (r >> 2) + 4 * half;
            sv = (kvb + kvloc <= myq) ? sv : -3e38f;
          }
          t[m * 16 + r] = sv;
        }
      float mx = fmaxf(t[0], t[1]);
#pragma unroll
      for (int i = 2; i < 32; i += 2) mx = fmaxf(fmaxf(mx, t[i]), t[i + 1]);
      mx = fmaxf(mx, __shfl_xor(mx, 32));

      if (!__all(mx <= m2 + 11.54f)) {  // defer-max (T13), 8*log2e
        const float mnew = fmaxf(m2, mx);
        const float rsc = __builtin_amdgcn_exp2f(m2 - mnew);
        m2 = mnew; l *= rsc;
#pragma unroll
        for (int r = 0; r < 16; ++r) {
          const int rowv = (r & 3) + 8 * (r >> 2) + 4 * half;
          const float f = __shfl(rsc, rowv);
          o[0][r] *= f; o[1][r] *= f; o[2][r] *= f; o[3][r] *= f;
        }
      }

      float ts = 0.f;
#pragma unroll
      for (int i = 0; i < 32; ++i) { t[i] = __builtin_amdgcn_exp2f(t[i] - m2); ts += t[i]; }
      ts += __shfl_xor(ts, 32);
      l += ts;

      // ---- pack P to bf16 word pairs ----
      unsigned wpk[2][4][2];
#pragma unroll
      for (int m = 0; m < 2; ++m)
#pragma unroll
        for (int r4 = 0; r4 < 4; ++r4) {
          wpk[m][r4][0] = pkbf(t[m * 16 + r4 * 4 + 0], t[m * 16 + r4 * 4 + 1]);
          wpk[m][r4][1] = pkbf(t[m * 16 + r4 * 4 + 2], t[m * 16 + r4 * 4 + 3]);
        }

      // wait V_t only (tile kt+1's 4 loads remain in flight)
      if (kt + 1 < ktN) asm volatile("s_waitcnt vmcnt(4)" ::: "memory");
      else              asm volatile("s_waitcnt vmcnt(0)" ::: "memory");
      __builtin_amdgcn_s_barrier();

      // ---- PV: exchange halves via shfl_xor(32) ----
      const char* vb = (const char*)&Vs[cur][0];
#pragma unroll
      for (int ks = 0; ks < 4; ++ks) {
        const int m = ks >> 1, i = ks & 1;
        const unsigned s0 = half ? wpk[m][2 * i][0] : wpk[m][2 * i + 1][0];
        const unsigned s1 = half ? wpk[m][2 * i][1] : wpk[m][2 * i + 1][1];
        const unsigned rv0 = (unsigned)__shfl_xor((int)s0, 32);
        const unsigned rv1 = (unsigned)__shfl_xor((int)s1, 32);
        const unsigned ow0 = half ? wpk[m][2 * i + 1][0] : wpk[m][2 * i][0];
        const unsigned ow1 = half ? wpk[m][2 * i + 1][1] : wpk[m][2 * i][1];
        union { unsigned u[4]; bf16x8 v; } fr;
        fr.u[0] = half ? rv0 : ow0;
        fr.u[1] = half ? rv1 : ow1;
        fr.u[2] = half ? ow0 : rv0;
        fr.u[3] = half ? ow1 : rv1;
        const int cd = ks * 2 + half;
        __builtin_amdgcn_s_setprio(1);
#pragma unroll
        for (int nf = 0; nf < 4; ++nf) {
          bf16x8 vf = *(const bf16x8*)(vb + vrow0 + nf * 4096 + ((cd ^ q7) << 4));
          o[nf] = __builtin_amdgcn_mfma_f32_32x32x16_bf16(fr.v, vf, o[nf], 0, 0, 0);
        }
        __builtin_amdgcn_s_setprio(0);
      }
    }

    // ---- partial epilogue: unnormalized O + (m,l) ----
    const int set = (bh * 8 + qt) * 4 + s4;     // [0, 1024)
    unsigned short* ob = (set < 512) ? Op0 + ((size_t)set << 15)
                                     : Op1 + ((size_t)(set - 512) << 15);
    if (half == 0) {
      Stats[(set << 9) + (w * 32 + q5) * 2] = m2;
      Stats[(set << 9) + (w * 32 + q5) * 2 + 1] = l;
    }
#pragma unroll
    for (int r = 0; r < 16; ++r) {
      const int rowv = (r & 3) + 8 * (r >> 2) + 4 * half;
      const int row = w * 32 + rowv;               // [0, 256)
#pragma unroll
      for (int nf = 0; nf < 4; ++nf)
        ob[row * 128 + nf * 32 + q5] = f2bf(o[nf][r]);
    }
  }
}

// ---------------- merge the four KV-split partials (m in log2 units) ----------------
__global__ __launch_bounds__(256) void mla_merge(const unsigned short* __restrict__ Op0,
                                                 const unsigned short* __restrict__ Op1,
                                                 const float* __restrict__ St,
                                                 unsigned short* __restrict__ AO) {
  const int idx = blockIdx.x * 256 + threadIdx.x;  // [0, 1048576)
  const int rid = idx >> 4;                        // row id [0, 65536)
  const int d0 = (idx & 15) << 3;
  const int bhqt = rid >> 8;                       // [0, 256)
  const int row = rid & 255;
  const int sb = bhqt << 2;
  float m[4], lv[4];
#pragma unroll
  for (int s = 0; s < 4; ++s) {
    m[s] = St[((sb + s) << 9) + row * 2];
    lv[s] = St[((sb + s) << 9) + row * 2 + 1];
  }
  const float M = fmaxf(fmaxf(m[0], m[1]), fmaxf(m[2], m[3]));
  float wgt[4], den = 0.f;
#pragma unroll
  for (int s = 0; s < 4; ++s) { wgt[s] = __builtin_amdgcn_exp2f(m[s] - M); den += wgt[s] * lv[s]; }
  const float inv = 1.0f / den;
  bf16x8 pa[4];
#pragma unroll
  for (int s = 0; s < 4; ++s) {
    const int set = sb + s;
    const unsigned short* p = (set < 512) ? Op0 + ((size_t)set << 15)
                                          : Op1 + ((size_t)(set - 512) << 15);
    pa[s] = *(const bf16x8*)(p + row * 128 + d0);
  }
  const int bh = bhqt >> 3, qt = bhqt & 7;
  const int head = bh & 15, b = bh >> 4;
  unsigned short outv[8];
#pragma unroll
  for (int j = 0; j < 8; ++j) {
    float acc = 0.f;
#pragma unroll
    for (int s = 0; s < 4; ++s) acc += wgt[s] * bf2f((unsigned short)pa[s][j]);
    outv[j] = f2bf(acc * inv);
  }
  unsigned short* dst = AO + ((size_t)(b * 2048 + qt * 256 + row)) * 2048 + head * 128 + d0;
  *(uint4*)dst = *(const uint4*)outv;
}

extern "C" void kernel_launch(void* const* d_in, const int* in_sizes, int n_in,
                              void* d_out, int out_size, void* d_ws, size_t ws_size,
                              hipStream_t stream) {
  const float* q    = (const float*)d_in[0];
  const float* lat  = (const float*)d_in[1];
  const float* Wq   = (const float*)d_in[2];
  const float* Wkv  = (const float*)d_in[3];
  const float* Wout = (const float*)d_in[4];

  char* ws = (char*)d_ws;
  // Phase A (cvt+projections): qbf[0,16M) Wqbf[16,24M) latbf[24,28M) Wkvbf[28,32M)
  // Phase B (attn): Op0[0,32M) + Stats[32M,34M) reuse dead cvt inputs + old Wobf slot;
  //                 Op1 = d_out (dead until final GEMM).
  // Phase C: aobf reuses Kbf; Wobf (cvt_w, post-attn) reuses VTbf region.
  unsigned short* qbf   = (unsigned short*)(ws);
  unsigned short* Op0   = (unsigned short*)(ws);             // 32 MiB
  unsigned short* Wqbf  = (unsigned short*)(ws + 16777216);
  unsigned short* latbf = (unsigned short*)(ws + 25165824);
  unsigned short* Wkvbf = (unsigned short*)(ws + 29360128);
  float*          Stats = (float*)(ws + 33554432);           // 2 MiB (old Wobf slot)
  unsigned short* qpbf  = (unsigned short*)(ws + 41943040);  // [4096,2048]
  unsigned short* Kbf   = (unsigned short*)(ws + 58720256);  // [4096,2048]
  unsigned short* aobf  = (unsigned short*)(ws + 58720256);  // reuses Kbf (dead after attn)
  unsigned short* VTbf  = (unsigned short*)(ws + 75497472);  // [2][2048][2048]
  unsigned short* Wobf  = (unsigned short*)(ws + 75497472);  // reuses VTbf (dead after attn)
  unsigned short* Wvbf  = Wkvbf + (size_t)2048 * 512;
  unsigned short* Op1   = (unsigned short*)d_out;            // 32 MiB (dead until final GEMM)

  // 1/sqrt(128) * log2(e): folds attention scale + exp->exp2 into qp
  const float SCALE_L2E = 0.12751742f;

  cvt_all<<<8192, 256, 0, stream>>>(q, Wq, lat, Wkv, qbf, Wqbf, latbf, Wkvbf);

  // qp = (q * Wq^T) * SCALE_L2E   (pre-scaled Q)
  gemm_bt<false><<<512, 256, 0, stream>>>(qbf, Wqbf, qpbf, 4096, 2048, 2048, 0, 0, SCALE_L2E);
  // K = latent * Wk^T   [4096,2048]
  gemm_bt<false><<<512, 256, 0, stream>>>(latbf, Wkvbf, Kbf, 4096, 2048, 512, 0, 0, 1.0f);
  // V^T = Wv * latent[b]^T, batched over b via blockIdx.z
  gemm_bt<false><<<dim3(256, 1, 2), 256, 0, stream>>>(
      Wvbf, latbf, VTbf, 2048, 2048, 512,
      (size_t)2048 * 512, (size_t)2048 * 2048, 1.0f);
  // attention: 512 blocks x 512 threads, 4-way KV-split partials
  mla_attn<<<512, 512, 0, stream>>>(qpbf, Kbf, VTbf, Op0, Op1, Stats);
  // Wout conversion into the now-dead VTbf region
  cvt_w<<<2048, 256, 0, stream>>>(Wout, Wobf);
  // merge 4 partials -> aobf
  mla_merge<<<4096, 256, 0, stream>>>(Op0, Op1, Stats, aobf);
  // out = ao * Wout^T -> f32 (overwrites every element of d_out)
  gemm_bt<true><<<512, 256, 0, stream>>>(aobf, Wobf, (float*)d_out, 4096, 2048, 2048, 0, 0, 1.0f);
}

// Round 14
// 241.527 us; speedup vs baseline: 1.3251x; 1.3251x over previous
//
#include <hip/hip_runtime.h>

#define SLEN 2048
#define NHEADS 16
#define HDIM 128

typedef __attribute__((ext_vector_type(8))) short bf16x8;
typedef __attribute__((ext_vector_type(4))) float f32x4;
typedef __attribute__((ext_vector_type(16))) float f32x16;

__device__ __forceinline__ unsigned short f2bf(float f) {
  union { float f; unsigned u; } v; v.f = f;
  unsigned r = v.u + 0x7FFFu + ((v.u >> 16) & 1u);
  return (unsigned short)(r >> 16);
}

__device__ __forceinline__ float bf2f(unsigned short h) {
  union { unsigned u; float f; } v; v.u = (unsigned)h << 16;
  return v.f;
}

__device__ __forceinline__ unsigned pkbf(float a, float b) {
  unsigned r;
  asm("v_cvt_pk_bf16_f32 %0, %1, %2" : "=v"(r) : "v"(a), "v"(b));
  return r;
}

__device__ __forceinline__ void gload16(const void* g, void* l) {
  __builtin_amdgcn_global_load_lds(
      (const __attribute__((address_space(1))) unsigned int*)g,
      (__attribute__((address_space(3))) unsigned int*)l, 16, 0, 0);
}

// ------------- fused f32 -> bf16 conversion for q, Wq, lat, Wkv -------------
__global__ __launch_bounds__(256) void cvt_all(const float* __restrict__ q,
                                               const float* __restrict__ Wq,
                                               const float* __restrict__ lat,
                                               const float* __restrict__ Wkv,
                                               unsigned short* __restrict__ qo,
                                               unsigned short* __restrict__ Wqo,
                                               unsigned short* __restrict__ lato,
                                               unsigned short* __restrict__ Wkvo) {
  const int blk = blockIdx.x;
  const float* in;
  unsigned short* out;
  int base;
  if (blk < 4096)      { in = q;    out = qo;    base = 0; }
  else if (blk < 6144) { in = Wq;   out = Wqo;   base = 4096; }
  else if (blk < 7168) { in = lat;  out = lato;  base = 6144; }
  else                 { in = Wkv;  out = Wkvo;  base = 7168; }
  const int i = (blk - base) * 256 + threadIdx.x;
  const float4* p = reinterpret_cast<const float4*>(in) + (size_t)i * 2;
  float4 a = p[0], b = p[1];
  uint4 o;
  o.x = (unsigned)f2bf(a.x) | ((unsigned)f2bf(a.y) << 16);
  o.y = (unsigned)f2bf(a.z) | ((unsigned)f2bf(a.w) << 16);
  o.z = (unsigned)f2bf(b.x) | ((unsigned)f2bf(b.y) << 16);
  o.w = (unsigned)f2bf(b.z) | ((unsigned)f2bf(b.w) << 16);
  reinterpret_cast<uint4*>(out)[i] = o;
}

// ------------- Wout conversion, deferred to after attention -------------
__global__ __launch_bounds__(256) void cvt_w(const float* __restrict__ in,
                                             unsigned short* __restrict__ out) {
  const int i = blockIdx.x * 256 + threadIdx.x;
  const float4* p = reinterpret_cast<const float4*>(in) + (size_t)i * 2;
  float4 a = p[0], b = p[1];
  uint4 o;
  o.x = (unsigned)f2bf(a.x) | ((unsigned)f2bf(a.y) << 16);
  o.y = (unsigned)f2bf(a.z) | ((unsigned)f2bf(a.w) << 16);
  o.z = (unsigned)f2bf(b.x) | ((unsigned)f2bf(b.y) << 16);
  o.w = (unsigned)f2bf(b.z) | ((unsigned)f2bf(b.w) << 16);
  reinterpret_cast<uint4*>(out)[i] = o;
}

// ---------------- C = A[M,K] * B[N,K]^T, bf16 in, f32 acc ----------------
// R8-verified: 128x128 tile, BK=32, 4-slot LDS ring (64 KiB), counted
// vmcnt(8) — never drains mid-loop; ONE raw barrier per iter. Both-sides
// XOR chunk swizzle. XCD swizzle (grid%8==0). blockIdx.z batches.
template <bool OUT_F32>
__global__ __launch_bounds__(256, 2) void gemm_bt(const unsigned short* __restrict__ A,
                                                  const unsigned short* __restrict__ B,
                                                  void* __restrict__ Cv,
                                                  int M, int N, int K,
                                                  size_t zB, size_t zC, float scale) {
  __shared__ unsigned short As[4][128 * 32];
  __shared__ unsigned short Bs[4][128 * 32];
  const int tid = threadIdx.x;
  const int lane = tid & 63, wid = tid >> 6;
  const int g = lane >> 4, q = lane & 15;
  const int nbx = N >> 7;
  const int cpx = gridDim.x >> 3;
  const int bid = (blockIdx.x & 7) * cpx + (blockIdx.x >> 3);
  const int bx = bid % nbx, by = bid / nbx;
  const int tM = by << 7, tN = bx << 7;
  const int wm = (wid >> 1) * 64, wn = (wid & 1) * 64;
  const size_t zoff = (size_t)blockIdx.z;
  B += zoff * zB;

  const int sr = tid >> 2, sc = tid & 3;
  const int scs = sc ^ (sr & 3);
  const unsigned short* gA0 = A + (size_t)(tM + sr) * K + (scs << 3);
  const unsigned short* gA1 = A + (size_t)(tM + 64 + sr) * K + (scs << 3);
  const unsigned short* gB0 = B + (size_t)(tN + sr) * K + (scs << 3);
  const unsigned short* gB1 = B + (size_t)(tN + 64 + sr) * K + (scs << 3);

  const int nk = K >> 5;
  const int gq = g ^ (q & 3);

  auto STAGE = [&](int slot, int kt) {
    const size_t ko = (size_t)kt << 5;
    unsigned short* ad = &As[slot][0] + tid * 8;
    unsigned short* bd = &Bs[slot][0] + tid * 8;
    gload16(gA0 + ko, ad);
    gload16(gA1 + ko, ad + 2048);
    gload16(gB0 + ko, bd);
    gload16(gB1 + ko, bd + 2048);
  };

  STAGE(0, 0); STAGE(1, 1); STAGE(2, 2);

  f32x4 acc[4][4] = {};

  for (int t = 0; t < nk; ++t) {
    if (t + 2 < nk)      asm volatile("s_waitcnt vmcnt(8)" ::: "memory");
    else if (t + 1 < nk) asm volatile("s_waitcnt vmcnt(4)" ::: "memory");
    else                 asm volatile("s_waitcnt vmcnt(0)" ::: "memory");
    __builtin_amdgcn_s_barrier();
    if (t + 3 < nk) STAGE((t + 3) & 3, t + 3);

    const int s = t & 3;
    bf16x8 af[4], bfr[4];
#pragma unroll
    for (int i = 0; i < 4; ++i)
      af[i] = *(const bf16x8*)&As[s][(wm + i * 16 + q) * 32 + gq * 8];
#pragma unroll
    for (int j = 0; j < 4; ++j)
      bfr[j] = *(const bf16x8*)&Bs[s][(wn + j * 16 + q) * 32 + gq * 8];
    __builtin_amdgcn_s_setprio(1);
#pragma unroll
    for (int i = 0; i < 4; ++i)
#pragma unroll
      for (int j = 0; j < 4; ++j)
        acc[i][j] = __builtin_amdgcn_mfma_f32_16x16x32_bf16(af[i], bfr[j], acc[i][j], 0, 0, 0);
    __builtin_amdgcn_s_setprio(0);
  }

  if constexpr (OUT_F32) {
    float* C = (float*)Cv + zoff * zC;
#pragma unroll
    for (int i = 0; i < 4; ++i)
#pragma unroll
      for (int j = 0; j < 4; ++j)
#pragma unroll
        for (int r = 0; r < 4; ++r)
          C[(size_t)(tM + wm + i * 16 + g * 4 + r) * N + (tN + wn + j * 16 + q)] =
              acc[i][j][r] * scale;
  } else {
    unsigned short* C = (unsigned short*)Cv + zoff * zC;
#pragma unroll
    for (int i = 0; i < 4; ++i)
#pragma unroll
      for (int j = 0; j < 4; ++j)
#pragma unroll
        for (int r = 0; r < 4; ++r)
          C[(size_t)(tM + wm + i * 16 + g * 4 + r) * N + (tN + wn + j * 16 + q)] =
              f2bf(acc[i][j][r] * scale);
  }
}

// ------------- causal flash attention, 8-wave blocks, 4-way KV-split -------------
// R13 geometry with FIXED launch bounds: (512, 2) -> VGPR cap 128 (need ~104,
// NO spills), 16 waves/CU = 2 blocks/CU. Grid 512 x 512 threads:
// s4 = bid&3, pr = (bid>>2)&3, bh = bid>>4. Block handles q-tiles {7-pr, pr}
// (256 rows, wave w owns rows w*32..), KV quarter s4 -> UNIFORM 9 iters.
// LDS 64 KiB (K dbuf 32K + V dbuf 32K). Per-thread staging: 2 K + 2 V loads
// per tile; top vmcnt(2)=K_t, post-softmax vmcnt(4)=V_t; next tile's 4 loads
// stay in flight. Same R8 inner math; XOR-swizzled K (^row&15) / VT (^row&7).
__global__ __launch_bounds__(512, 2) void mla_attn(const unsigned short* __restrict__ Q,
                                                   const unsigned short* __restrict__ K,
                                                   const unsigned short* __restrict__ VT,
                                                   unsigned short* __restrict__ Op0,
                                                   unsigned short* __restrict__ Op1,
                                                   float* __restrict__ Stats) {
  __shared__ unsigned short Ks[2][64 * 128];   // [kv][d], swizzled, 32 KiB
  __shared__ unsigned short Vs[2][128 * 64];   // [d][kv], swizzled, 32 KiB

  const int tid = threadIdx.x, lane = tid & 63, w = tid >> 6;  // w in [0,8)
  const int q5 = lane & 31, half = lane >> 5, q7 = lane & 7;
  const int s4 = blockIdx.x & 3;
  const int pr = (blockIdx.x >> 2) & 3;
  const int bh = blockIdx.x >> 4;
  const int head = bh & 15, b = bh >> 4;

  const unsigned short* Kbase = K + (size_t)(b * 2048) * 2048 + head * 128;
  const unsigned short* Vbase = VT + (size_t)(b * 2048 + head * 128) * 2048;

  // staging source coords (pre-swizzled); 512 thr cover a 64x128 tile in 2 loads
  const int r0 = tid >> 4, c0 = tid & 15;               // K: rows r0, r0+32
  const unsigned short* kS = Kbase + (size_t)r0 * 2048 + ((c0 ^ (r0 & 15)) << 3);
  const int d0 = tid >> 3, c3 = tid & 7;                // VT: rows d0, d0+64
  const unsigned short* vS = Vbase + (size_t)d0 * 2048 + ((c3 ^ (d0 & 7)) << 3);

  const int arow0 = q5 * 256;   // K LDS row byte base (+ m*8192)
  const int vrow0 = q5 * 128;   // VT LDS row byte base (+ nf*4096)
  const int q15 = q5 & 15;      // K read-side swizzle term (row&15)

  for (int t2 = 0; t2 < 2; ++t2) {
    const int qt = t2 ? pr : 7 - pr;
    const int kt0 = (qt + 1) * s4;        // KVBLK=64 tiles; T = 4(qt+1) split 4 ways
    const int ktN = (qt + 1) * (s4 + 1);
    const int myq = qt * 256 + w * 32 + q5;
    const unsigned short* Qrow = Q + (size_t)(b * 2048 + myq) * 2048 + head * 128;

    bf16x8 qf[8];
#pragma unroll
    for (int ks = 0; ks < 8; ++ks)
      qf[ks] = *(const bf16x8*)((const char*)Qrow + ks * 32 + half * 16);

    __syncthreads();  // protect LDS against previous q-tile's readers

    // prologue: stage tile kt0 (K loads first, then V -- FIFO order matters)
    {
      unsigned short* kd = &Ks[kt0 & 1][0] + tid * 8;
      unsigned short* vd = &Vs[kt0 & 1][0] + tid * 8;
      const unsigned short* ks2 = kS + (size_t)(kt0 * 64) * 2048;
      const unsigned short* vs2 = vS + kt0 * 64;
      gload16(ks2, kd);
      gload16(ks2 + (size_t)32 * 2048, kd + 4096);
      gload16(vs2, vd);
      gload16(vs2 + (size_t)64 * 2048, vd + 4096);
    }

    float m2 = -1e30f, l = 0.f;
    f32x16 o[4];
#pragma unroll
    for (int i = 0; i < 16; ++i) { o[0][i] = 0.f; o[1][i] = 0.f; o[2][i] = 0.f; o[3][i] = 0.f; }

    for (int kt = kt0; kt < ktN; ++kt) {
      const int cur = kt & 1;
      // wait K_t only (V_t + next tile's loads stay in flight)
      asm volatile("s_waitcnt vmcnt(2)" ::: "memory");
      __builtin_amdgcn_s_barrier();

      if (kt + 1 < ktN) {  // stage tile kt+1: K first, then V
        unsigned short* kd = &Ks[cur ^ 1][0] + tid * 8;
        unsigned short* vd = &Vs[cur ^ 1][0] + tid * 8;
        const unsigned short* ks2 = kS + (size_t)((kt + 1) * 64) * 2048;
        const unsigned short* vs2 = vS + (kt + 1) * 64;
        gload16(ks2, kd);
        gload16(ks2 + (size_t)32 * 2048, kd + 4096);
        gload16(vs2, vd);
        gload16(vs2 + (size_t)64 * 2048, vd + 4096);
      }

      // ---- QK^T: St[kv][q], A = K rows (LDS), B = Q (regs, pre-scaled) ----
      f32x16 st[2];
#pragma unroll
      for (int i = 0; i < 16; ++i) { st[0][i] = 0.f; st[1][i] = 0.f; }
      const char* kb = (const char*)&Ks[cur][0];
      __builtin_amdgcn_s_setprio(1);
#pragma unroll
      for (int ks = 0; ks < 8; ++ks) {
        const int cd = ks * 2 + half;
#pragma unroll
        for (int m = 0; m < 2; ++m) {
          bf16x8 kf = *(const bf16x8*)(kb + arow0 + m * 8192 + ((cd ^ q15) << 4));
          st[m] = __builtin_amdgcn_mfma_f32_32x32x16_bf16(kf, qf[ks], st[m], 0, 0, 0);
        }
      }
      __builtin_amdgcn_s_setprio(0);

      // ---- softmax in exp2 space (lane owns q-col q5; 32 kv values) ----
      float t[32];
      const int kvb = kt * 64;
      const bool needmask = (kvb + 63 > qt * 256 + w * 32);
#pragma unroll
      for (int m = 0; m < 2; ++m)
#pragma unroll
        for (int r = 0; r < 16; ++r) {
          float sv = st[m][r];
          if (needmask) {
            const int kvloc = m * 32 + (r & 3) + 8 * (r >> 2) + 4 * half;
            sv = (kvb + kvloc <= myq) ? sv : -3e38f;
          }
          t[m * 16 + r] = sv;
        }
      float mx = fmaxf(t[0], t[1]);
#pragma unroll
      for (int i = 2; i < 32; i += 2) mx = fmaxf(fmaxf(mx, t[i]), t[i + 1]);
      mx = fmaxf(mx, __shfl_xor(mx, 32));

      if (!__all(mx <= m2 + 11.54f)) {  // defer-max (T13), 8*log2e
        const float mnew = fmaxf(m2, mx);
        const float rsc = __builtin_amdgcn_exp2f(m2 - mnew);
        m2 = mnew; l *= rsc;
#pragma unroll
        for (int r = 0; r < 16; ++r) {
          const int rowv = (r & 3) + 8 * (r >> 2) + 4 * half;
          const float f = __shfl(rsc, rowv);
          o[0][r] *= f; o[1][r] *= f; o[2][r] *= f; o[3][r] *= f;
        }
      }

      float ts = 0.f;
#pragma unroll
      for (int i = 0; i < 32; ++i) { t[i] = __builtin_amdgcn_exp2f(t[i] - m2); ts += t[i]; }
      ts += __shfl_xor(ts, 32);
      l += ts;

      // ---- pack P to bf16 word pairs ----
      unsigned wpk[2][4][2];
#pragma unroll
      for (int m = 0; m < 2; ++m)
#pragma unroll
        for (int r4 = 0; r4 < 4; ++r4) {
          wpk[m][r4][0] = pkbf(t[m * 16 + r4 * 4 + 0], t[m * 16 + r4 * 4 + 1]);
          wpk[m][r4][1] = pkbf(t[m * 16 + r4 * 4 + 2], t[m * 16 + r4 * 4 + 3]);
        }

      // wait V_t only (tile kt+1's 4 loads remain in flight)
      if (kt + 1 < ktN) asm volatile("s_waitcnt vmcnt(4)" ::: "memory");
      else              asm volatile("s_waitcnt vmcnt(0)" ::: "memory");
      __builtin_amdgcn_s_barrier();

      // ---- PV: exchange halves via shfl_xor(32) ----
      const char* vb = (const char*)&Vs[cur][0];
#pragma unroll
      for (int ks = 0; ks < 4; ++ks) {
        const int m = ks >> 1, i = ks & 1;
        const unsigned s0 = half ? wpk[m][2 * i][0] : wpk[m][2 * i + 1][0];
        const unsigned s1 = half ? wpk[m][2 * i][1] : wpk[m][2 * i + 1][1];
        const unsigned rv0 = (unsigned)__shfl_xor((int)s0, 32);
        const unsigned rv1 = (unsigned)__shfl_xor((int)s1, 32);
        const unsigned ow0 = half ? wpk[m][2 * i + 1][0] : wpk[m][2 * i][0];
        const unsigned ow1 = half ? wpk[m][2 * i + 1][1] : wpk[m][2 * i][1];
        union { unsigned u[4]; bf16x8 v; } fr;
        fr.u[0] = half ? rv0 : ow0;
        fr.u[1] = half ? rv1 : ow1;
        fr.u[2] = half ? ow0 : rv0;
        fr.u[3] = half ? ow1 : rv1;
        const int cd = ks * 2 + half;
        __builtin_amdgcn_s_setprio(1);
#pragma unroll
        for (int nf = 0; nf < 4; ++nf) {
          bf16x8 vf = *(const bf16x8*)(vb + vrow0 + nf * 4096 + ((cd ^ q7) << 4));
          o[nf] = __builtin_amdgcn_mfma_f32_32x32x16_bf16(fr.v, vf, o[nf], 0, 0, 0);
        }
        __builtin_amdgcn_s_setprio(0);
      }
    }

    // ---- partial epilogue: unnormalized O + (m,l) ----
    const int set = (bh * 8 + qt) * 4 + s4;     // [0, 1024)
    unsigned short* ob = (set < 512) ? Op0 + ((size_t)set << 15)
                                     : Op1 + ((size_t)(set - 512) << 15);
    if (half == 0) {
      Stats[(set << 9) + (w * 32 + q5) * 2] = m2;
      Stats[(set << 9) + (w * 32 + q5) * 2 + 1] = l;
    }
#pragma unroll
    for (int r = 0; r < 16; ++r) {
      const int rowv = (r & 3) + 8 * (r >> 2) + 4 * half;
      const int row = w * 32 + rowv;               // [0, 256)
#pragma unroll
      for (int nf = 0; nf < 4; ++nf)
        ob[row * 128 + nf * 32 + q5] = f2bf(o[nf][r]);
    }
  }
}

// ---------------- merge the four KV-split partials (m in log2 units) ----------------
__global__ __launch_bounds__(256) void mla_merge(const unsigned short* __restrict__ Op0,
                                                 const unsigned short* __restrict__ Op1,
                                                 const float* __restrict__ St,
                                                 unsigned short* __restrict__ AO) {
  const int idx = blockIdx.x * 256 + threadIdx.x;  // [0, 1048576)
  const int rid = idx >> 4;                        // row id [0, 65536)
  const int d0 = (idx & 15) << 3;
  const int bhqt = rid >> 8;                       // [0, 256)
  const int row = rid & 255;
  const int sb = bhqt << 2;
  float m[4], lv[4];
#pragma unroll
  for (int s = 0; s < 4; ++s) {
    m[s] = St[((sb + s) << 9) + row * 2];
    lv[s] = St[((sb + s) << 9) + row * 2 + 1];
  }
  const float M = fmaxf(fmaxf(m[0], m[1]), fmaxf(m[2], m[3]));
  float wgt[4], den = 0.f;
#pragma unroll
  for (int s = 0; s < 4; ++s) { wgt[s] = __builtin_amdgcn_exp2f(m[s] - M); den += wgt[s] * lv[s]; }
  const float inv = 1.0f / den;
  bf16x8 pa[4];
#pragma unroll
  for (int s = 0; s < 4; ++s) {
    const int set = sb + s;
    const unsigned short* p = (set < 512) ? Op0 + ((size_t)set << 15)
                                          : Op1 + ((size_t)(set - 512) << 15);
    pa[s] = *(const bf16x8*)(p + row * 128 + d0);
  }
  const int bh = bhqt >> 3, qt = bhqt & 7;
  const int head = bh & 15, b = bh >> 4;
  unsigned short outv[8];
#pragma unroll
  for (int j = 0; j < 8; ++j) {
    float acc = 0.f;
#pragma unroll
    for (int s = 0; s < 4; ++s) acc += wgt[s] * bf2f((unsigned short)pa[s][j]);
    outv[j] = f2bf(acc * inv);
  }
  unsigned short* dst = AO + ((size_t)(b * 2048 + qt * 256 + row)) * 2048 + head * 128 + d0;
  *(uint4*)dst = *(const uint4*)outv;
}

extern "C" void kernel_launch(void* const* d_in, const int* in_sizes, int n_in,
                              void* d_out, int out_size, void* d_ws, size_t ws_size,
                              hipStream_t stream) {
  const float* q    = (const float*)d_in[0];
  const float* lat  = (const float*)d_in[1];
  const float* Wq   = (const float*)d_in[2];
  const float* Wkv  = (const float*)d_in[3];
  const float* Wout = (const float*)d_in[4];

  char* ws = (char*)d_ws;
  // Phase A (cvt+projections): qbf[0,16M) Wqbf[16,24M) latbf[24,28M) Wkvbf[28,32M)
  // Phase B (attn): Op0[0,32M) + Stats[32M,34M); Op1 = d_out.
  // Phase C: aobf reuses Kbf; Wobf (cvt_w, post-attn) reuses VTbf region.
  unsigned short* qbf   = (unsigned short*)(ws);
  unsigned short* Op0   = (unsigned short*)(ws);             // 32 MiB
  unsigned short* Wqbf  = (unsigned short*)(ws + 16777216);
  unsigned short* latbf = (unsigned short*)(ws + 25165824);
  unsigned short* Wkvbf = (unsigned short*)(ws + 29360128);
  float*          Stats = (float*)(ws + 33554432);           // 2 MiB
  unsigned short* qpbf  = (unsigned short*)(ws + 41943040);  // [4096,2048]
  unsigned short* Kbf   = (unsigned short*)(ws + 58720256);  // [4096,2048]
  unsigned short* aobf  = (unsigned short*)(ws + 58720256);  // reuses Kbf
  unsigned short* VTbf  = (unsigned short*)(ws + 75497472);  // [2][2048][2048]
  unsigned short* Wobf  = (unsigned short*)(ws + 75497472);  // reuses VTbf
  unsigned short* Wvbf  = Wkvbf + (size_t)2048 * 512;
  unsigned short* Op1   = (unsigned short*)d_out;            // 32 MiB

  // 1/sqrt(128) * log2(e): folds attention scale + exp->exp2 into qp
  const float SCALE_L2E = 0.12751742f;

  cvt_all<<<8192, 256, 0, stream>>>(q, Wq, lat, Wkv, qbf, Wqbf, latbf, Wkvbf);

  // qp = (q * Wq^T) * SCALE_L2E   (pre-scaled Q)
  gemm_bt<false><<<512, 256, 0, stream>>>(qbf, Wqbf, qpbf, 4096, 2048, 2048, 0, 0, SCALE_L2E);
  // K = latent * Wk^T   [4096,2048]
  gemm_bt<false><<<512, 256, 0, stream>>>(latbf, Wkvbf, Kbf, 4096, 2048, 512, 0, 0, 1.0f);
  // V^T = Wv * latent[b]^T, batched over b via blockIdx.z
  gemm_bt<false><<<dim3(256, 1, 2), 256, 0, stream>>>(
      Wvbf, latbf, VTbf, 2048, 2048, 512,
      (size_t)2048 * 512, (size_t)2048 * 2048, 1.0f);
  // attention: 512 blocks x 512 threads, 4-way KV-split partials
  mla_attn<<<512, 512, 0, stream>>>(qpbf, Kbf, VTbf, Op0, Op1, Stats);
  // Wout conversion into the now-dead VTbf region
  cvt_w<<<2048, 256, 0, stream>>>(Wout, Wobf);
  // merge 4 partials -> aobf
  mla_merge<<<4096, 256, 0, stream>>>(Op0, Op1, Stats, aobf);
  // out = ao * Wout^T -> f32 (overwrites every element of d_out)
  gemm_bt<true><<<512, 256, 0, stream>>>(aobf, Wobf, (float*)d_out, 4096, 2048, 2048, 0, 0, 1.0f);
}

// Round 15
// 222.559 us; speedup vs baseline: 1.4381x; 1.0852x over previous
//
#include <hip/hip_runtime.h>

#define SLEN 2048
#define NHEADS 16
#define HDIM 128

typedef __attribute__((ext_vector_type(8))) short bf16x8;
typedef __attribute__((ext_vector_type(4))) float f32x4;
typedef __attribute__((ext_vector_type(16))) float f32x16;

__device__ __forceinline__ unsigned short f2bf(float f) {
  union { float f; unsigned u; } v; v.f = f;
  unsigned r = v.u + 0x7FFFu + ((v.u >> 16) & 1u);
  return (unsigned short)(r >> 16);
}

__device__ __forceinline__ float bf2f(unsigned short h) {
  union { unsigned u; float f; } v; v.u = (unsigned)h << 16;
  return v.f;
}

__device__ __forceinline__ unsigned pkbf(float a, float b) {
  unsigned r;
  asm("v_cvt_pk_bf16_f32 %0, %1, %2" : "=v"(r) : "v"(a), "v"(b));
  return r;
}

__device__ __forceinline__ void gload16(const void* g, void* l) {
  __builtin_amdgcn_global_load_lds(
      (const __attribute__((address_space(1))) unsigned int*)g,
      (__attribute__((address_space(3))) unsigned int*)l, 16, 0, 0);
}

// ------------- fused f32 -> bf16 conversion for all 5 inputs -------------
__global__ __launch_bounds__(256) void cvt_all(const float* __restrict__ q,
                                               const float* __restrict__ Wq,
                                               const float* __restrict__ lat,
                                               const float* __restrict__ Wkv,
                                               const float* __restrict__ Wout,
                                               unsigned short* __restrict__ qo,
                                               unsigned short* __restrict__ Wqo,
                                               unsigned short* __restrict__ lato,
                                               unsigned short* __restrict__ Wkvo,
                                               unsigned short* __restrict__ Wouto) {
  const int blk = blockIdx.x;
  const float* in;
  unsigned short* out;
  int base;
  if (blk < 4096)      { in = q;    out = qo;    base = 0; }
  else if (blk < 6144) { in = Wq;   out = Wqo;   base = 4096; }
  else if (blk < 7168) { in = lat;  out = lato;  base = 6144; }
  else if (blk < 8192) { in = Wkv;  out = Wkvo;  base = 7168; }
  else                 { in = Wout; out = Wouto; base = 8192; }
  const int i = (blk - base) * 256 + threadIdx.x;
  const float4* p = reinterpret_cast<const float4*>(in) + (size_t)i * 2;
  float4 a = p[0], b = p[1];
  uint4 o;
  o.x = (unsigned)f2bf(a.x) | ((unsigned)f2bf(a.y) << 16);
  o.y = (unsigned)f2bf(a.z) | ((unsigned)f2bf(a.w) << 16);
  o.z = (unsigned)f2bf(b.x) | ((unsigned)f2bf(b.y) << 16);
  o.w = (unsigned)f2bf(b.z) | ((unsigned)f2bf(b.w) << 16);
  reinterpret_cast<uint4*>(out)[i] = o;
}

// ---------------- C = A[M,K] * B[N,K]^T, bf16 in, f32 acc ----------------
// 128x128 tile, BK=32, 4-slot LDS ring (64 KiB), counted vmcnt(8) — never
// drains mid-loop; ONE raw barrier per iter. Stage t+3 lands in the slot
// freed at t-1. Both-sides XOR chunk swizzle. XCD swizzle (grid%8==0).
// blockIdx.z batches: B += z*zB, C += z*zC. Epilogue multiplies by `scale`.
template <bool OUT_F32>
__global__ __launch_bounds__(256, 2) void gemm_bt(const unsigned short* __restrict__ A,
                                                  const unsigned short* __restrict__ B,
                                                  void* __restrict__ Cv,
                                                  int M, int N, int K,
                                                  size_t zB, size_t zC, float scale) {
  __shared__ unsigned short As[4][128 * 32];
  __shared__ unsigned short Bs[4][128 * 32];
  const int tid = threadIdx.x;
  const int lane = tid & 63, wid = tid >> 6;
  const int g = lane >> 4, q = lane & 15;
  const int nbx = N >> 7;
  const int cpx = gridDim.x >> 3;
  const int bid = (blockIdx.x & 7) * cpx + (blockIdx.x >> 3);
  const int bx = bid % nbx, by = bid / nbx;
  const int tM = by << 7, tN = bx << 7;
  const int wm = (wid >> 1) * 64, wn = (wid & 1) * 64;
  const size_t zoff = (size_t)blockIdx.z;
  B += zoff * zB;

  const int sr = tid >> 2, sc = tid & 3;
  const int scs = sc ^ (sr & 3);
  const unsigned short* gA0 = A + (size_t)(tM + sr) * K + (scs << 3);
  const unsigned short* gA1 = A + (size_t)(tM + 64 + sr) * K + (scs << 3);
  const unsigned short* gB0 = B + (size_t)(tN + sr) * K + (scs << 3);
  const unsigned short* gB1 = B + (size_t)(tN + 64 + sr) * K + (scs << 3);

  const int nk = K >> 5;
  const int gq = g ^ (q & 3);

  auto STAGE = [&](int slot, int kt) {
    const size_t ko = (size_t)kt << 5;
    unsigned short* ad = &As[slot][0] + tid * 8;
    unsigned short* bd = &Bs[slot][0] + tid * 8;
    gload16(gA0 + ko, ad);
    gload16(gA1 + ko, ad + 2048);
    gload16(gB0 + ko, bd);
    gload16(gB1 + ko, bd + 2048);
  };

  STAGE(0, 0); STAGE(1, 1); STAGE(2, 2);

  f32x4 acc[4][4] = {};

  for (int t = 0; t < nk; ++t) {
    if (t + 2 < nk)      asm volatile("s_waitcnt vmcnt(8)" ::: "memory");
    else if (t + 1 < nk) asm volatile("s_waitcnt vmcnt(4)" ::: "memory");
    else                 asm volatile("s_waitcnt vmcnt(0)" ::: "memory");
    __builtin_amdgcn_s_barrier();
    if (t + 3 < nk) STAGE((t + 3) & 3, t + 3);

    const int s = t & 3;
    bf16x8 af[4], bfr[4];
#pragma unroll
    for (int i = 0; i < 4; ++i)
      af[i] = *(const bf16x8*)&As[s][(wm + i * 16 + q) * 32 + gq * 8];
#pragma unroll
    for (int j = 0; j < 4; ++j)
      bfr[j] = *(const bf16x8*)&Bs[s][(wn + j * 16 + q) * 32 + gq * 8];
    __builtin_amdgcn_s_setprio(1);
#pragma unroll
    for (int i = 0; i < 4; ++i)
#pragma unroll
      for (int j = 0; j < 4; ++j)
        acc[i][j] = __builtin_amdgcn_mfma_f32_16x16x32_bf16(af[i], bfr[j], acc[i][j], 0, 0, 0);
    __builtin_amdgcn_s_setprio(0);
  }

  if constexpr (OUT_F32) {
    float* C = (float*)Cv + zoff * zC;
#pragma unroll
    for (int i = 0; i < 4; ++i)
#pragma unroll
      for (int j = 0; j < 4; ++j)
#pragma unroll
        for (int r = 0; r < 4; ++r)
          C[(size_t)(tM + wm + i * 16 + g * 4 + r) * N + (tN + wn + j * 16 + q)] =
              acc[i][j][r] * scale;
  } else {
    unsigned short* C = (unsigned short*)Cv + zoff * zC;
#pragma unroll
    for (int i = 0; i < 4; ++i)
#pragma unroll
      for (int j = 0; j < 4; ++j)
#pragma unroll
        for (int r = 0; r < 4; ++r)
          C[(size_t)(tM + wm + i * 16 + g * 4 + r) * N + (tN + wn + j * 16 + q)] =
              f2bf(acc[i][j][r] * scale);
  }
}

// ---------------- causal flash attention, 32x32 MFMA, 2-way KV-split ----------------
// R8-verified best: Grid 512: s = bid&1, pr = (bid>>1)&7, bh = bid>>4. Block
// handles q-tiles {15-pr, pr} sequentially, KV-half s of each -> UNIFORM 17
// iters/block, 2 blocks/CU (64 KiB LDS). Q pre-scaled by 1/sqrt(d)*log2e;
// softmax in exp2 space. Counted split waits: stage = K(4) then V(4); iter
// top vmcnt(4) (K_t only), after softmax vmcnt(8) (V_t only) — next tile's
// 8 loads stay in flight across both waits. XOR-swizzled K (^row&15) /
// VT (^row&7) on pre-swizzled source AND ds_read.
__global__ __launch_bounds__(256, 2) void mla_attn(const unsigned short* __restrict__ Q,
                                                   const unsigned short* __restrict__ K,
                                                   const unsigned short* __restrict__ VT,
                                                   unsigned short* __restrict__ Opart,
                                                   float* __restrict__ Stats) {
  __shared__ unsigned short Ks[2][64 * 128];   // [kv][d], swizzled
  __shared__ unsigned short Vs[2][128 * 64];   // [d][kv], swizzled

  const int tid = threadIdx.x, lane = tid & 63, w = tid >> 6;
  const int q5 = lane & 31, half = lane >> 5, q7 = lane & 7;
  const int s = blockIdx.x & 1;
  const int pr = (blockIdx.x >> 1) & 7;
  const int bh = blockIdx.x >> 4;
  const int head = bh & 15, b = bh >> 4;

  const unsigned short* Kbase = K + (size_t)(b * 2048) * 2048 + head * 128;
  const unsigned short* Vbase = VT + (size_t)(b * 2048 + head * 128) * 2048;

  const int r0 = tid >> 4, c0 = tid & 15;               // K: 16 chunks/row
  const unsigned short* kS = Kbase + (size_t)r0 * 2048 + ((c0 ^ r0) << 3);
  const int d0 = tid >> 3, c3 = tid & 7;                // VT: 8 chunks/row
  const unsigned short* vS = Vbase + (size_t)d0 * 2048 + ((c3 ^ (d0 & 7)) << 3);

  const int arow0 = q5 * 256;   // K LDS row byte base (+ m*8192)
  const int vrow0 = q5 * 128;   // VT LDS row byte base (+ nf*4096)
  const int q15 = q5 & 15;      // K read-side swizzle term (row&15)

  for (int t2 = 0; t2 < 2; ++t2) {
    const int qt = t2 ? pr : 15 - pr;
    const int kt0 = s * (qt + 1);
    const int ktN = kt0 + qt + 1;
    const int myq = qt * 128 + w * 32 + q5;
    const unsigned short* Qrow = Q + (size_t)(b * 2048 + myq) * 2048 + head * 128;

    bf16x8 qf[8];
#pragma unroll
    for (int ks = 0; ks < 8; ++ks)
      qf[ks] = *(const bf16x8*)((const char*)Qrow + ks * 32 + half * 16);

    __syncthreads();  // protect LDS against previous q-tile's readers

    // prologue: stage tile kt0 (K loads first, then V -- FIFO order matters)
    {
      const int kvb0 = kt0 * 64;
      unsigned short* kd = &Ks[kt0 & 1][0] + tid * 8;
      unsigned short* vd = &Vs[kt0 & 1][0] + tid * 8;
      const unsigned short* ks2 = kS + (size_t)kvb0 * 2048;
      const unsigned short* vs2 = vS + kvb0;
#pragma unroll
      for (int u = 0; u < 4; ++u) gload16(ks2 + (size_t)u * 16 * 2048, kd + u * 2048);
#pragma unroll
      for (int u = 0; u < 4; ++u) gload16(vs2 + (size_t)u * 32 * 2048, vd + u * 2048);
    }

    float m2 = -1e30f, l = 0.f;
    f32x16 o[4];
#pragma unroll
    for (int i = 0; i < 16; ++i) { o[0][i] = 0.f; o[1][i] = 0.f; o[2][i] = 0.f; o[3][i] = 0.f; }

    for (int kt = kt0; kt < ktN; ++kt) {
      const int cur = kt & 1;
      // wait K_t only (V_t + next tile's loads stay in flight)
      asm volatile("s_waitcnt vmcnt(4)" ::: "memory");
      __builtin_amdgcn_s_barrier();

      if (kt + 1 < ktN) {  // stage tile kt+1: K first, then V
        const int kvb2 = (kt + 1) * 64;
        unsigned short* kd = &Ks[cur ^ 1][0] + tid * 8;
        unsigned short* vd = &Vs[cur ^ 1][0] + tid * 8;
        const unsigned short* ks2 = kS + (size_t)kvb2 * 2048;
        const unsigned short* vs2 = vS + kvb2;
#pragma unroll
        for (int u = 0; u < 4; ++u) gload16(ks2 + (size_t)u * 16 * 2048, kd + u * 2048);
#pragma unroll
        for (int u = 0; u < 4; ++u) gload16(vs2 + (size_t)u * 32 * 2048, vd + u * 2048);
      }

      // ---- QK^T: St[kv][q], A = K rows (LDS), B = Q (regs, pre-scaled) ----
      f32x16 st[2];
#pragma unroll
      for (int i = 0; i < 16; ++i) { st[0][i] = 0.f; st[1][i] = 0.f; }
      const char* kb = (const char*)&Ks[cur][0];
      __builtin_amdgcn_s_setprio(1);
#pragma unroll
      for (int ks = 0; ks < 8; ++ks) {
        const int cd = ks * 2 + half;
#pragma unroll
        for (int m = 0; m < 2; ++m) {
          bf16x8 kf = *(const bf16x8*)(kb + arow0 + m * 8192 + ((cd ^ q15) << 4));
          st[m] = __builtin_amdgcn_mfma_f32_32x32x16_bf16(kf, qf[ks], st[m], 0, 0, 0);
        }
      }
      __builtin_amdgcn_s_setprio(0);

      // ---- softmax in exp2 space (lane owns q-col q5; 32 kv values) ----
      float t[32];
      const int kvb = kt * 64;
      const bool needmask = (kvb + 63 > qt * 128 + w * 32);
#pragma unroll
      for (int m = 0; m < 2; ++m)
#pragma unroll
        for (int r = 0; r < 16; ++r) {
          float sv = st[m][r];
          if (needmask) {
            const int kvloc = m * 32 + (r & 3) + 8 * (r >> 2) + 4 * half;
            sv = (kvb + kvloc <= myq) ? sv : -3e38f;
          }
          t[m * 16 + r] = sv;
        }
      float mx = fmaxf(t[0], t[1]);
#pragma unroll
      for (int i = 2; i < 32; i += 2) mx = fmaxf(fmaxf(mx, t[i]), t[i + 1]);
      mx = fmaxf(mx, __shfl_xor(mx, 32));

      if (!__all(mx <= m2 + 11.54f)) {  // defer-max (T13), 8*log2e
        const float mnew = fmaxf(m2, mx);
        const float rsc = __builtin_amdgcn_exp2f(m2 - mnew);
        m2 = mnew; l *= rsc;
#pragma unroll
        for (int r = 0; r < 16; ++r) {
          const int rowv = (r & 3) + 8 * (r >> 2) + 4 * half;
          const float f = __shfl(rsc, rowv);
          o[0][r] *= f; o[1][r] *= f; o[2][r] *= f; o[3][r] *= f;
        }
      }

      float ts = 0.f;
#pragma unroll
      for (int i = 0; i < 32; ++i) { t[i] = __builtin_amdgcn_exp2f(t[i] - m2); ts += t[i]; }
      ts += __shfl_xor(ts, 32);
      l += ts;

      // ---- pack P to bf16 word pairs ----
      unsigned wpk[2][4][2];
#pragma unroll
      for (int m = 0; m < 2; ++m)
#pragma unroll
        for (int r4 = 0; r4 < 4; ++r4) {
          wpk[m][r4][0] = pkbf(t[m * 16 + r4 * 4 + 0], t[m * 16 + r4 * 4 + 1]);
          wpk[m][r4][1] = pkbf(t[m * 16 + r4 * 4 + 2], t[m * 16 + r4 * 4 + 3]);
        }

      // wait V_t only (tile kt+1's 8 loads remain in flight)
      if (kt + 1 < ktN) asm volatile("s_waitcnt vmcnt(8)" ::: "memory");
      else              asm volatile("s_waitcnt vmcnt(0)" ::: "memory");
      __builtin_amdgcn_s_barrier();

      // ---- PV: exchange halves via shfl_xor(32) ----
      const char* vb = (const char*)&Vs[cur][0];
#pragma unroll
      for (int ks = 0; ks < 4; ++ks) {
        const int m = ks >> 1, i = ks & 1;
        const unsigned s0 = half ? wpk[m][2 * i][0] : wpk[m][2 * i + 1][0];
        const unsigned s1 = half ? wpk[m][2 * i][1] : wpk[m][2 * i + 1][1];
        const unsigned rv0 = (unsigned)__shfl_xor((int)s0, 32);
        const unsigned rv1 = (unsigned)__shfl_xor((int)s1, 32);
        const unsigned ow0 = half ? wpk[m][2 * i + 1][0] : wpk[m][2 * i][0];
        const unsigned ow1 = half ? wpk[m][2 * i + 1][1] : wpk[m][2 * i][1];
        union { unsigned u[4]; bf16x8 v; } fr;
        fr.u[0] = half ? rv0 : ow0;
        fr.u[1] = half ? rv1 : ow1;
        fr.u[2] = half ? ow0 : rv0;
        fr.u[3] = half ? ow1 : rv1;
        const int cd = ks * 2 + half;
        __builtin_amdgcn_s_setprio(1);
#pragma unroll
        for (int nf = 0; nf < 4; ++nf) {
          bf16x8 vf = *(const bf16x8*)(vb + vrow0 + nf * 4096 + ((cd ^ q7) << 4));
          o[nf] = __builtin_amdgcn_mfma_f32_32x32x16_bf16(fr.v, vf, o[nf], 0, 0, 0);
        }
        __builtin_amdgcn_s_setprio(0);
      }
    }

    // ---- partial epilogue: unnormalized O + (m,l) ----
    const int set = (bh * 16 + qt) * 2 + s;
    const int base_o = set << 14;
    const int base_s = set << 8;
    if (half == 0) {
      Stats[base_s + (w * 32 + q5) * 2] = m2;
      Stats[base_s + (w * 32 + q5) * 2 + 1] = l;
    }
#pragma unroll
    for (int r = 0; r < 16; ++r) {
      const int rowv = (r & 3) + 8 * (r >> 2) + 4 * half;
      const int row = w * 32 + rowv;
#pragma unroll
      for (int nf = 0; nf < 4; ++nf)
        Opart[base_o + row * 128 + nf * 32 + q5] = f2bf(o[nf][r]);
    }
  }
}

// ---------------- merge the two KV-half partials (m in log2 units) ----------------
__global__ __launch_bounds__(256) void mla_merge(const unsigned short* __restrict__ Op,
                                                 const float* __restrict__ St,
                                                 unsigned short* __restrict__ AO) {
  const int idx = blockIdx.x * 256 + threadIdx.x;
  const int rid = idx >> 4;
  const int d0 = (idx & 15) << 3;
  const int bhqt = rid >> 7;
  const int row = rid & 127;
  const int sb = bhqt << 1;
  const float m1 = St[(sb << 8) + row * 2];
  const float l1 = St[(sb << 8) + row * 2 + 1];
  const float m2 = St[(sb << 8) + 256 + row * 2];
  const float l2 = St[(sb << 8) + 256 + row * 2 + 1];
  const float M = fmaxf(m1, m2);
  const float w1 = __builtin_amdgcn_exp2f(m1 - M);
  const float w2 = __builtin_amdgcn_exp2f(m2 - M);
  const float inv = 1.0f / (w1 * l1 + w2 * l2);
  const unsigned short* p1 = Op + ((size_t)sb << 14) + row * 128 + d0;
  bf16x8 a = *(const bf16x8*)p1;
  bf16x8 c = *(const bf16x8*)(p1 + 16384);
  const int bh = bhqt >> 4, qt = bhqt & 15;
  const int head = bh & 15, b = bh >> 4;
  unsigned short outv[8];
#pragma unroll
  for (int j = 0; j < 8; ++j)
    outv[j] = f2bf((w1 * bf2f((unsigned short)a[j]) + w2 * bf2f((unsigned short)c[j])) * inv);
  unsigned short* dst = AO + ((size_t)(b * 2048 + qt * 128 + row)) * 2048 + head * 128 + d0;
  *(uint4*)dst = *(const uint4*)outv;
}

extern "C" void kernel_launch(void* const* d_in, const int* in_sizes, int n_in,
                              void* d_out, int out_size, void* d_ws, size_t ws_size,
                              hipStream_t stream) {
  const float* q    = (const float*)d_in[0];
  const float* lat  = (const float*)d_in[1];
  const float* Wq   = (const float*)d_in[2];
  const float* Wkv  = (const float*)d_in[3];
  const float* Wout = (const float*)d_in[4];

  char* ws = (char*)d_ws;
  unsigned short* qbf   = (unsigned short*)(ws);
  unsigned short* Opart = (unsigned short*)(ws);             // 32 MiB, reuses cvt inputs
  unsigned short* Wqbf  = (unsigned short*)(ws + 16777216);
  unsigned short* latbf = (unsigned short*)(ws + 25165824);
  unsigned short* Wkvbf = (unsigned short*)(ws + 29360128);
  unsigned short* Wobf  = (unsigned short*)(ws + 33554432);
  unsigned short* qpbf  = (unsigned short*)(ws + 41943040);  // [4096,2048]
  unsigned short* Kbf   = (unsigned short*)(ws + 58720256);  // [4096,2048]
  unsigned short* aobf  = (unsigned short*)(ws + 58720256);  // reuses Kbf
  unsigned short* VTbf  = (unsigned short*)(ws + 75497472);  // [2][2048][2048]
  float*          Stats = (float*)(ws + 92274688);           // 1 MiB
  unsigned short* Wvbf  = Wkvbf + (size_t)2048 * 512;

  // 1/sqrt(128) * log2(e): folds attention scale + exp->exp2 into qp
  const float SCALE_L2E = 0.12751742f;

  cvt_all<<<10240, 256, 0, stream>>>(q, Wq, lat, Wkv, Wout,
                                     qbf, Wqbf, latbf, Wkvbf, Wobf);

  // qp = (q * Wq^T) * SCALE_L2E   (pre-scaled Q)
  gemm_bt<false><<<512, 256, 0, stream>>>(qbf, Wqbf, qpbf, 4096, 2048, 2048, 0, 0, SCALE_L2E);
  // K = latent * Wk^T   [4096,2048]
  gemm_bt<false><<<512, 256, 0, stream>>>(latbf, Wkvbf, Kbf, 4096, 2048, 512, 0, 0, 1.0f);
  // V^T = Wv * latent[b]^T, batched over b via blockIdx.z
  gemm_bt<false><<<dim3(256, 1, 2), 256, 0, stream>>>(
      Wvbf, latbf, VTbf, 2048, 2048, 512,
      (size_t)2048 * 512, (size_t)2048 * 2048, 1.0f);
  // attention (partials) + merge
  mla_attn<<<512, 256, 0, stream>>>(qpbf, Kbf, VTbf, Opart, Stats);
  mla_merge<<<4096, 256, 0, stream>>>(Opart, Stats, aobf);
  // out = ao * Wout^T -> f32
  gemm_bt<true><<<512, 256, 0, stream>>>(aobf, Wobf, (float*)d_out, 4096, 2048, 2048, 0, 0, 1.0f);
}

// Round 16
// 215.760 us; speedup vs baseline: 1.4834x; 1.0315x over previous
//
#include <hip/hip_runtime.h>

#define SLEN 2048
#define NHEADS 16
#define HDIM 128

typedef __attribute__((ext_vector_type(8))) short bf16x8;
typedef __attribute__((ext_vector_type(4))) float f32x4;
typedef __attribute__((ext_vector_type(16))) float f32x16;

__device__ __forceinline__ unsigned short f2bf(float f) {
  union { float f; unsigned u; } v; v.f = f;
  unsigned r = v.u + 0x7FFFu + ((v.u >> 16) & 1u);
  return (unsigned short)(r >> 16);
}

__device__ __forceinline__ float bf2f(unsigned short h) {
  union { unsigned u; float f; } v; v.u = (unsigned)h << 16;
  return v.f;
}

__device__ __forceinline__ unsigned pkbf(float a, float b) {
  unsigned r;
  asm("v_cvt_pk_bf16_f32 %0, %1, %2" : "=v"(r) : "v"(a), "v"(b));
  return r;
}

__device__ __forceinline__ void gload16(const void* g, void* l) {
  __builtin_amdgcn_global_load_lds(
      (const __attribute__((address_space(1))) unsigned int*)g,
      (__attribute__((address_space(3))) unsigned int*)l, 16, 0, 0);
}

// ------------- fused f32 -> bf16 conversion for all 5 inputs -------------
__global__ __launch_bounds__(256) void cvt_all(const float* __restrict__ q,
                                               const float* __restrict__ Wq,
                                               const float* __restrict__ lat,
                                               const float* __restrict__ Wkv,
                                               const float* __restrict__ Wout,
                                               unsigned short* __restrict__ qo,
                                               unsigned short* __restrict__ Wqo,
                                               unsigned short* __restrict__ lato,
                                               unsigned short* __restrict__ Wkvo,
                                               unsigned short* __restrict__ Wouto) {
  const int blk = blockIdx.x;
  const float* in;
  unsigned short* out;
  int base;
  if (blk < 4096)      { in = q;    out = qo;    base = 0; }
  else if (blk < 6144) { in = Wq;   out = Wqo;   base = 4096; }
  else if (blk < 7168) { in = lat;  out = lato;  base = 6144; }
  else if (blk < 8192) { in = Wkv;  out = Wkvo;  base = 7168; }
  else                 { in = Wout; out = Wouto; base = 8192; }
  const int i = (blk - base) * 256 + threadIdx.x;
  const float4* p = reinterpret_cast<const float4*>(in) + (size_t)i * 2;
  float4 a = p[0], b = p[1];
  uint4 o;
  o.x = (unsigned)f2bf(a.x) | ((unsigned)f2bf(a.y) << 16);
  o.y = (unsigned)f2bf(a.z) | ((unsigned)f2bf(a.w) << 16);
  o.z = (unsigned)f2bf(b.x) | ((unsigned)f2bf(b.y) << 16);
  o.w = (unsigned)f2bf(b.z) | ((unsigned)f2bf(b.w) << 16);
  reinterpret_cast<uint4*>(out)[i] = o;
}

// ---------------- C = A[M,K] * B[N,K]^T, bf16 in, f32 acc ----------------
// 128x128 tile, BK=32, 4-slot LDS ring (64 KiB), counted vmcnt(8) — never
// drains mid-loop; ONE raw barrier per iter. Stage t+3 lands in the slot
// freed at t-1. Both-sides XOR chunk swizzle. XCD swizzle (grid%8==0).
// blockIdx.z batches: B += z*zB, C += z*zC. Epilogue multiplies by `scale`.
template <bool OUT_F32>
__global__ __launch_bounds__(256, 2) void gemm_bt(const unsigned short* __restrict__ A,
                                                  const unsigned short* __restrict__ B,
                                                  void* __restrict__ Cv,
                                                  int M, int N, int K,
                                                  size_t zB, size_t zC, float scale) {
  __shared__ unsigned short As[4][128 * 32];
  __shared__ unsigned short Bs[4][128 * 32];
  const int tid = threadIdx.x;
  const int lane = tid & 63, wid = tid >> 6;
  const int g = lane >> 4, q = lane & 15;
  const int nbx = N >> 7;
  const int cpx = gridDim.x >> 3;
  const int bid = (blockIdx.x & 7) * cpx + (blockIdx.x >> 3);
  const int bx = bid % nbx, by = bid / nbx;
  const int tM = by << 7, tN = bx << 7;
  const int wm = (wid >> 1) * 64, wn = (wid & 1) * 64;
  const size_t zoff = (size_t)blockIdx.z;
  B += zoff * zB;

  const int sr = tid >> 2, sc = tid & 3;
  const int scs = sc ^ (sr & 3);
  const unsigned short* gA0 = A + (size_t)(tM + sr) * K + (scs << 3);
  const unsigned short* gA1 = A + (size_t)(tM + 64 + sr) * K + (scs << 3);
  const unsigned short* gB0 = B + (size_t)(tN + sr) * K + (scs << 3);
  const unsigned short* gB1 = B + (size_t)(tN + 64 + sr) * K + (scs << 3);

  const int nk = K >> 5;
  const int gq = g ^ (q & 3);

  auto STAGE = [&](int slot, int kt) {
    const size_t ko = (size_t)kt << 5;
    unsigned short* ad = &As[slot][0] + tid * 8;
    unsigned short* bd = &Bs[slot][0] + tid * 8;
    gload16(gA0 + ko, ad);
    gload16(gA1 + ko, ad + 2048);
    gload16(gB0 + ko, bd);
    gload16(gB1 + ko, bd + 2048);
  };

  STAGE(0, 0); STAGE(1, 1); STAGE(2, 2);

  f32x4 acc[4][4] = {};

  for (int t = 0; t < nk; ++t) {
    if (t + 2 < nk)      asm volatile("s_waitcnt vmcnt(8)" ::: "memory");
    else if (t + 1 < nk) asm volatile("s_waitcnt vmcnt(4)" ::: "memory");
    else                 asm volatile("s_waitcnt vmcnt(0)" ::: "memory");
    __builtin_amdgcn_s_barrier();
    if (t + 3 < nk) STAGE((t + 3) & 3, t + 3);

    const int s = t & 3;
    bf16x8 af[4], bfr[4];
#pragma unroll
    for (int i = 0; i < 4; ++i)
      af[i] = *(const bf16x8*)&As[s][(wm + i * 16 + q) * 32 + gq * 8];
#pragma unroll
    for (int j = 0; j < 4; ++j)
      bfr[j] = *(const bf16x8*)&Bs[s][(wn + j * 16 + q) * 32 + gq * 8];
    __builtin_amdgcn_s_setprio(1);
#pragma unroll
    for (int i = 0; i < 4; ++i)
#pragma unroll
      for (int j = 0; j < 4; ++j)
        acc[i][j] = __builtin_amdgcn_mfma_f32_16x16x32_bf16(af[i], bfr[j], acc[i][j], 0, 0, 0);
    __builtin_amdgcn_s_setprio(0);
  }

  if constexpr (OUT_F32) {
    float* C = (float*)Cv + zoff * zC;
#pragma unroll
    for (int i = 0; i < 4; ++i)
#pragma unroll
      for (int j = 0; j < 4; ++j)
#pragma unroll
        for (int r = 0; r < 4; ++r)
          C[(size_t)(tM + wm + i * 16 + g * 4 + r) * N + (tN + wn + j * 16 + q)] =
              acc[i][j][r] * scale;
  } else {
    unsigned short* C = (unsigned short*)Cv + zoff * zC;
#pragma unroll
    for (int i = 0; i < 4; ++i)
#pragma unroll
      for (int j = 0; j < 4; ++j)
#pragma unroll
        for (int r = 0; r < 4; ++r)
          C[(size_t)(tM + wm + i * 16 + g * 4 + r) * N + (tN + wn + j * 16 + q)] =
              f2bf(acc[i][j][r] * scale);
  }
}

// ---------------- causal flash attention, 32x32 MFMA, 2-way KV-split ----------------
// R8 structure + XCD-chunked block swizzle: newbid = (bid&7)*64 + bid>>3
// (bijective, 512 = 8 x 64). XCD x receives a contiguous 64-block chunk =
// 4 complete bh groups = 4 MB of K/V -> fits its private 4 MB L2 (T1).
// Then s = nb&1, pr = (nb>>1)&7, bh = nb>>4 as before. Block handles q-tiles
// {15-pr, pr} sequentially, KV-half s of each -> UNIFORM 17 iters/block,
// 2 blocks/CU (64 KiB LDS). Q pre-scaled by 1/sqrt(d)*log2e; softmax in exp2
// space. Counted split waits: iter top vmcnt(4) (K_t), post-softmax vmcnt(8)
// (V_t); next tile's 8 loads stay in flight. XOR-swizzled K/VT both sides.
__global__ __launch_bounds__(256, 2) void mla_attn(const unsigned short* __restrict__ Q,
                                                   const unsigned short* __restrict__ K,
                                                   const unsigned short* __restrict__ VT,
                                                   unsigned short* __restrict__ Opart,
                                                   float* __restrict__ Stats) {
  __shared__ unsigned short Ks[2][64 * 128];   // [kv][d], swizzled
  __shared__ unsigned short Vs[2][128 * 64];   // [d][kv], swizzled

  const int tid = threadIdx.x, lane = tid & 63, w = tid >> 6;
  const int q5 = lane & 31, half = lane >> 5, q7 = lane & 7;
  const int nb = (blockIdx.x & 7) * 64 + (blockIdx.x >> 3);  // XCD-chunked remap
  const int s = nb & 1;
  const int pr = (nb >> 1) & 7;
  const int bh = nb >> 4;
  const int head = bh & 15, b = bh >> 4;

  const unsigned short* Kbase = K + (size_t)(b * 2048) * 2048 + head * 128;
  const unsigned short* Vbase = VT + (size_t)(b * 2048 + head * 128) * 2048;

  const int r0 = tid >> 4, c0 = tid & 15;               // K: 16 chunks/row
  const unsigned short* kS = Kbase + (size_t)r0 * 2048 + ((c0 ^ r0) << 3);
  const int d0 = tid >> 3, c3 = tid & 7;                // VT: 8 chunks/row
  const unsigned short* vS = Vbase + (size_t)d0 * 2048 + ((c3 ^ (d0 & 7)) << 3);

  const int arow0 = q5 * 256;   // K LDS row byte base (+ m*8192)
  const int vrow0 = q5 * 128;   // VT LDS row byte base (+ nf*4096)
  const int q15 = q5 & 15;      // K read-side swizzle term (row&15)

  for (int t2 = 0; t2 < 2; ++t2) {
    const int qt = t2 ? pr : 15 - pr;
    const int kt0 = s * (qt + 1);
    const int ktN = kt0 + qt + 1;
    const int myq = qt * 128 + w * 32 + q5;
    const unsigned short* Qrow = Q + (size_t)(b * 2048 + myq) * 2048 + head * 128;

    bf16x8 qf[8];
#pragma unroll
    for (int ks = 0; ks < 8; ++ks)
      qf[ks] = *(const bf16x8*)((const char*)Qrow + ks * 32 + half * 16);

    __syncthreads();  // protect LDS against previous q-tile's readers

    // prologue: stage tile kt0 (K loads first, then V -- FIFO order matters)
    {
      const int kvb0 = kt0 * 64;
      unsigned short* kd = &Ks[kt0 & 1][0] + tid * 8;
      unsigned short* vd = &Vs[kt0 & 1][0] + tid * 8;
      const unsigned short* ks2 = kS + (size_t)kvb0 * 2048;
      const unsigned short* vs2 = vS + kvb0;
#pragma unroll
      for (int u = 0; u < 4; ++u) gload16(ks2 + (size_t)u * 16 * 2048, kd + u * 2048);
#pragma unroll
      for (int u = 0; u < 4; ++u) gload16(vs2 + (size_t)u * 32 * 2048, vd + u * 2048);
    }

    float m2 = -1e30f, l = 0.f;
    f32x16 o[4];
#pragma unroll
    for (int i = 0; i < 16; ++i) { o[0][i] = 0.f; o[1][i] = 0.f; o[2][i] = 0.f; o[3][i] = 0.f; }

    for (int kt = kt0; kt < ktN; ++kt) {
      const int cur = kt & 1;
      // wait K_t only (V_t + next tile's loads stay in flight)
      asm volatile("s_waitcnt vmcnt(4)" ::: "memory");
      __builtin_amdgcn_s_barrier();

      if (kt + 1 < ktN) {  // stage tile kt+1: K first, then V
        const int kvb2 = (kt + 1) * 64;
        unsigned short* kd = &Ks[cur ^ 1][0] + tid * 8;
        unsigned short* vd = &Vs[cur ^ 1][0] + tid * 8;
        const unsigned short* ks2 = kS + (size_t)kvb2 * 2048;
        const unsigned short* vs2 = vS + kvb2;
#pragma unroll
        for (int u = 0; u < 4; ++u) gload16(ks2 + (size_t)u * 16 * 2048, kd + u * 2048);
#pragma unroll
        for (int u = 0; u < 4; ++u) gload16(vs2 + (size_t)u * 32 * 2048, vd + u * 2048);
      }

      // ---- QK^T: St[kv][q], A = K rows (LDS), B = Q (regs, pre-scaled) ----
      f32x16 st[2];
#pragma unroll
      for (int i = 0; i < 16; ++i) { st[0][i] = 0.f; st[1][i] = 0.f; }
      const char* kb = (const char*)&Ks[cur][0];
      __builtin_amdgcn_s_setprio(1);
#pragma unroll
      for (int ks = 0; ks < 8; ++ks) {
        const int cd = ks * 2 + half;
#pragma unroll
        for (int m = 0; m < 2; ++m) {
          bf16x8 kf = *(const bf16x8*)(kb + arow0 + m * 8192 + ((cd ^ q15) << 4));
          st[m] = __builtin_amdgcn_mfma_f32_32x32x16_bf16(kf, qf[ks], st[m], 0, 0, 0);
        }
      }
      __builtin_amdgcn_s_setprio(0);

      // ---- softmax in exp2 space (lane owns q-col q5; 32 kv values) ----
      float t[32];
      const int kvb = kt * 64;
      const bool needmask = (kvb + 63 > qt * 128 + w * 32);
#pragma unroll
      for (int m = 0; m < 2; ++m)
#pragma unroll
        for (int r = 0; r < 16; ++r) {
          float sv = st[m][r];
          if (needmask) {
            const int kvloc = m * 32 + (r & 3) + 8 * (r >> 2) + 4 * half;
            sv = (kvb + kvloc <= myq) ? sv : -3e38f;
          }
          t[m * 16 + r] = sv;
        }
      float mx = fmaxf(t[0], t[1]);
#pragma unroll
      for (int i = 2; i < 32; i += 2) mx = fmaxf(fmaxf(mx, t[i]), t[i + 1]);
      mx = fmaxf(mx, __shfl_xor(mx, 32));

      if (!__all(mx <= m2 + 11.54f)) {  // defer-max (T13), 8*log2e
        const float mnew = fmaxf(m2, mx);
        const float rsc = __builtin_amdgcn_exp2f(m2 - mnew);
        m2 = mnew; l *= rsc;
#pragma unroll
        for (int r = 0; r < 16; ++r) {
          const int rowv = (r & 3) + 8 * (r >> 2) + 4 * half;
          const float f = __shfl(rsc, rowv);
          o[0][r] *= f; o[1][r] *= f; o[2][r] *= f; o[3][r] *= f;
        }
      }

      float ts = 0.f;
#pragma unroll
      for (int i = 0; i < 32; ++i) { t[i] = __builtin_amdgcn_exp2f(t[i] - m2); ts += t[i]; }
      ts += __shfl_xor(ts, 32);
      l += ts;

      // ---- pack P to bf16 word pairs ----
      unsigned wpk[2][4][2];
#pragma unroll
      for (int m = 0; m < 2; ++m)
#pragma unroll
        for (int r4 = 0; r4 < 4; ++r4) {
          wpk[m][r4][0] = pkbf(t[m * 16 + r4 * 4 + 0], t[m * 16 + r4 * 4 + 1]);
          wpk[m][r4][1] = pkbf(t[m * 16 + r4 * 4 + 2], t[m * 16 + r4 * 4 + 3]);
        }

      // wait V_t only (tile kt+1's 8 loads remain in flight)
      if (kt + 1 < ktN) asm volatile("s_waitcnt vmcnt(8)" ::: "memory");
      else              asm volatile("s_waitcnt vmcnt(0)" ::: "memory");
      __builtin_amdgcn_s_barrier();

      // ---- PV: exchange halves via shfl_xor(32) ----
      const char* vb = (const char*)&Vs[cur][0];
#pragma unroll
      for (int ks = 0; ks < 4; ++ks) {
        const int m = ks >> 1, i = ks & 1;
        const unsigned s0 = half ? wpk[m][2 * i][0] : wpk[m][2 * i + 1][0];
        const unsigned s1 = half ? wpk[m][2 * i][1] : wpk[m][2 * i + 1][1];
        const unsigned rv0 = (unsigned)__shfl_xor((int)s0, 32);
        const unsigned rv1 = (unsigned)__shfl_xor((int)s1, 32);
        const unsigned ow0 = half ? wpk[m][2 * i + 1][0] : wpk[m][2 * i][0];
        const unsigned ow1 = half ? wpk[m][2 * i + 1][1] : wpk[m][2 * i][1];
        union { unsigned u[4]; bf16x8 v; } fr;
        fr.u[0] = half ? rv0 : ow0;
        fr.u[1] = half ? rv1 : ow1;
        fr.u[2] = half ? ow0 : rv0;
        fr.u[3] = half ? ow1 : rv1;
        const int cd = ks * 2 + half;
        __builtin_amdgcn_s_setprio(1);
#pragma unroll
        for (int nf = 0; nf < 4; ++nf) {
          bf16x8 vf = *(const bf16x8*)(vb + vrow0 + nf * 4096 + ((cd ^ q7) << 4));
          o[nf] = __builtin_amdgcn_mfma_f32_32x32x16_bf16(fr.v, vf, o[nf], 0, 0, 0);
        }
        __builtin_amdgcn_s_setprio(0);
      }
    }

    // ---- partial epilogue: unnormalized O + (m,l) ----
    const int set = (bh * 16 + qt) * 2 + s;
    const int base_o = set << 14;
    const int base_s = set << 8;
    if (half == 0) {
      Stats[base_s + (w * 32 + q5) * 2] = m2;
      Stats[base_s + (w * 32 + q5) * 2 + 1] = l;
    }
#pragma unroll
    for (int r = 0; r < 16; ++r) {
      const int rowv = (r & 3) + 8 * (r >> 2) + 4 * half;
      const int row = w * 32 + rowv;
#pragma unroll
      for (int nf = 0; nf < 4; ++nf)
        Opart[base_o + row * 128 + nf * 32 + q5] = f2bf(o[nf][r]);
    }
  }
}

// ---------------- merge the two KV-half partials (m in log2 units) ----------------
__global__ __launch_bounds__(256) void mla_merge(const unsigned short* __restrict__ Op,
                                                 const float* __restrict__ St,
                                                 unsigned short* __restrict__ AO) {
  const int idx = blockIdx.x * 256 + threadIdx.x;
  const int rid = idx >> 4;
  const int d0 = (idx & 15) << 3;
  const int bhqt = rid >> 7;
  const int row = rid & 127;
  const int sb = bhqt << 1;
  const float m1 = St[(sb << 8) + row * 2];
  const float l1 = St[(sb << 8) + row * 2 + 1];
  const float m2 = St[(sb << 8) + 256 + row * 2];
  const float l2 = St[(sb << 8) + 256 + row * 2 + 1];
  const float M = fmaxf(m1, m2);
  const float w1 = __builtin_amdgcn_exp2f(m1 - M);
  const float w2 = __builtin_amdgcn_exp2f(m2 - M);
  const float inv = 1.0f / (w1 * l1 + w2 * l2);
  const unsigned short* p1 = Op + ((size_t)sb << 14) + row * 128 + d0;
  bf16x8 a = *(const bf16x8*)p1;
  bf16x8 c = *(const bf16x8*)(p1 + 16384);
  const int bh = bhqt >> 4, qt = bhqt & 15;
  const int head = bh & 15, b = bh >> 4;
  unsigned short outv[8];
#pragma unroll
  for (int j = 0; j < 8; ++j)
    outv[j] = f2bf((w1 * bf2f((unsigned short)a[j]) + w2 * bf2f((unsigned short)c[j])) * inv);
  unsigned short* dst = AO + ((size_t)(b * 2048 + qt * 128 + row)) * 2048 + head * 128 + d0;
  *(uint4*)dst = *(const uint4*)outv;
}

extern "C" void kernel_launch(void* const* d_in, const int* in_sizes, int n_in,
                              void* d_out, int out_size, void* d_ws, size_t ws_size,
                              hipStream_t stream) {
  const float* q    = (const float*)d_in[0];
  const float* lat  = (const float*)d_in[1];
  const float* Wq   = (const float*)d_in[2];
  const float* Wkv  = (const float*)d_in[3];
  const float* Wout = (const float*)d_in[4];

  char* ws = (char*)d_ws;
  unsigned short* qbf   = (unsigned short*)(ws);
  unsigned short* Opart = (unsigned short*)(ws);             // 32 MiB, reuses cvt inputs
  unsigned short* Wqbf  = (unsigned short*)(ws + 16777216);
  unsigned short* latbf = (unsigned short*)(ws + 25165824);
  unsigned short* Wkvbf = (unsigned short*)(ws + 29360128);
  unsigned short* Wobf  = (unsigned short*)(ws + 33554432);
  unsigned short* qpbf  = (unsigned short*)(ws + 41943040);  // [4096,2048]
  unsigned short* Kbf   = (unsigned short*)(ws + 58720256);  // [4096,2048]
  unsigned short* aobf  = (unsigned short*)(ws + 58720256);  // reuses Kbf
  unsigned short* VTbf  = (unsigned short*)(ws + 75497472);  // [2][2048][2048]
  float*          Stats = (float*)(ws + 92274688);           // 1 MiB
  unsigned short* Wvbf  = Wkvbf + (size_t)2048 * 512;

  // 1/sqrt(128) * log2(e): folds attention scale + exp->exp2 into qp
  const float SCALE_L2E = 0.12751742f;

  cvt_all<<<10240, 256, 0, stream>>>(q, Wq, lat, Wkv, Wout,
                                     qbf, Wqbf, latbf, Wkvbf, Wobf);

  // qp = (q * Wq^T) * SCALE_L2E   (pre-scaled Q)
  gemm_bt<false><<<512, 256, 0, stream>>>(qbf, Wqbf, qpbf, 4096, 2048, 2048, 0, 0, SCALE_L2E);
  // K = latent * Wk^T   [4096,2048]
  gemm_bt<false><<<512, 256, 0, stream>>>(latbf, Wkvbf, Kbf, 4096, 2048, 512, 0, 0, 1.0f);
  // V^T = Wv * latent[b]^T, batched over b via blockIdx.z
  gemm_bt<false><<<dim3(256, 1, 2), 256, 0, stream>>>(
      Wvbf, latbf, VTbf, 2048, 2048, 512,
      (size_t)2048 * 512, (size_t)2048 * 2048, 1.0f);
  // attention (partials, XCD-chunked swizzle) + merge
  mla_attn<<<512, 256, 0, stream>>>(qpbf, Kbf, VTbf, Opart, Stats);
  mla_merge<<<4096, 256, 0, stream>>>(Opart, Stats, aobf);
  // out = ao * Wout^T -> f32
  gemm_bt<true><<<512, 256, 0, stream>>>(aobf, Wobf, (float*)d_out, 4096, 2048, 2048, 0, 0, 1.0f);
}